// Round 2
// baseline (623.244 us; speedup 1.0000x reference)
//
#include <hip/hip_runtime.h>
#include <stdint.h>

// RzLinear: out[M,N] = x[M,K] @ W[K,N] + bias, W[k,n] = table[((k*r3+n*r2+r1)%P)%H]
// P compile-time prime; H = 2^20 so %H is a mask.
// R2: fuse build_wt + cvt_x into one mixed-grid kernel (overlap gather-latency
// work with streaming-BW work; one fewer launch). GEMM (m97 structure, 799 TF)
// unchanged.

#define P_CONST 56598313u
#define HASH_MASK 0xFFFFFu
#define M_DIM 8192
#define N_DIM 4096
#define K_DIM 4096

typedef __attribute__((ext_vector_type(8))) short bf16x8;
typedef __attribute__((ext_vector_type(4))) float f32x4;

__device__ __forceinline__ unsigned short f2bf(float f) {
    unsigned int u = __float_as_uint(f);
    return (unsigned short)((u + 0x7FFFu + ((u >> 16) & 1u)) >> 16);  // RNE
}

struct RN { unsigned long long r1, r2, r3; };

// random_numbers = [P, r1, r2, r3]; reference dtype is int64 but hedge for int32.
__device__ __forceinline__ RN decode_rn(const void* rn_raw) {
    RN o;
    const long long* rn64 = (const long long*)rn_raw;
    if (rn64[0] == 56598313LL) {
        o.r1 = (unsigned long long)rn64[1];
        o.r2 = (unsigned long long)rn64[2];
        o.r3 = (unsigned long long)rn64[3];
    } else {
        const int* rn32 = (const int*)rn_raw;
        o.r1 = (unsigned long long)(unsigned int)rn32[1];
        o.r2 = (unsigned long long)(unsigned int)rn32[2];
        o.r3 = (unsigned long long)(unsigned int)rn32[3];
    }
    return o;
}

// direct global->LDS, 16B per lane (wave-uniform LDS base + lane*16)
__device__ __forceinline__ void load16(const void* g, void* l) {
    __builtin_amdgcn_global_load_lds(
        (const __attribute__((address_space(1))) void*)g,
        (__attribute__((address_space(3))) void*)l,
        16, 0, 0);
}

// -------- Phase 1 (fused): Wt[n][k] = bf16(table[hash(k,n)]) and Xb = bf16(x)
// Grid = 20480 blocks: b%5==0 -> Wt row b/5 (4096 rows); else cvt chunk.
// Interleaving mixes latency-bound gather blocks with BW-bound stream blocks
// on every CU so the pipes overlap (time ~ max, not sum).
__global__ __launch_bounds__(256) void prep(const float* __restrict__ x,
                                            const float* __restrict__ table,
                                            const void* __restrict__ rn_raw,
                                            unsigned short* __restrict__ Wt,
                                            unsigned short* __restrict__ Xb) {
    const int b = blockIdx.x;
    const int t = threadIdx.x;
    if (b % 5 == 0) {
        // ---- hash-gather one Wt row ----
        RN rn = decode_rn(rn_raw);
        const unsigned int stepu = (unsigned int)(rn.r3 % P_CONST);
        const unsigned int n = (unsigned int)(b / 5);
        const unsigned long long base =
            ((unsigned long long)n * rn.r2 + rn.r1) % P_CONST;
#pragma unroll
        for (int e = 0; e < 2; ++e) {
            const int k0 = (t + e * 256) * 8;
            unsigned int cur =
                (unsigned int)((base + (unsigned long long)k0 * stepu) % P_CONST);
            union { unsigned short s[8]; uint4 v; } o;
#pragma unroll
            for (int i = 0; i < 8; ++i) {
                o.s[i] = f2bf(table[cur & HASH_MASK]);
                cur += stepu;
                if (cur >= P_CONST) cur -= P_CONST;
            }
            *(uint4*)(Wt + (size_t)n * K_DIM + k0) = o.v;
        }
    } else {
        // ---- stream-convert an x chunk (2048 floats/block) ----
        const int cb = b - (b / 5) - 1;  // 0..16383
        const size_t i8 = ((size_t)cb * 256 + t) * 8;
        const float4 a = *(const float4*)(x + i8);
        const float4 bb = *(const float4*)(x + i8 + 4);
        union { unsigned short s[8]; uint4 v; } o;
        o.s[0] = f2bf(a.x);  o.s[1] = f2bf(a.y);
        o.s[2] = f2bf(a.z);  o.s[3] = f2bf(a.w);
        o.s[4] = f2bf(bb.x); o.s[5] = f2bf(bb.y);
        o.s[6] = f2bf(bb.z); o.s[7] = f2bf(bb.w);
        *(uint4*)(Xb + i8) = o.v;
    }
}

// ---------------- Phase 2: C = A @ Bt^T + bias (m97 structure) ----------------
// A: [M][K] bf16 row-major, Bt: [N][K] bf16 row-major (so B-frags are contiguous).
// 128x128 tile, BK=32, 4 waves in 2x2, each wave 4x4 of 16x16x32 MFMA.
__global__ __launch_bounds__(256) void gemm_bt(const unsigned short* __restrict__ A,
                                               const unsigned short* __restrict__ Bt,
                                               const float* __restrict__ bias,
                                               float* __restrict__ C) {
    __shared__ __align__(16) unsigned short lA[128 * 32];
    __shared__ __align__(16) unsigned short lB[128 * 32];
    const int t = threadIdx.x;
    const int m0 = blockIdx.y * 128;
    const int n0 = blockIdx.x * 128;
    const int lane = t & 63;
    const int w = t >> 6;
    const int wr = w >> 1, wc = w & 1;
    const int lm = lane & 15, q = lane >> 4;

    f32x4 acc[4][4] = {};

    for (int k0 = 0; k0 < K_DIM; k0 += 32) {
#pragma unroll
        for (int c = t; c < 512; c += 256) {
            const unsigned short* gp =
                A + (size_t)(m0 + (c >> 2)) * K_DIM + k0 + (c & 3) * 8;
            load16(gp, (char*)lA + (size_t)c * 16);
        }
#pragma unroll
        for (int c = t; c < 512; c += 256) {
            const unsigned short* gp =
                Bt + (size_t)(n0 + (c >> 2)) * K_DIM + k0 + (c & 3) * 8;
            load16(gp, (char*)lB + (size_t)c * 16);
        }
        __syncthreads();

        bf16x8 af[4], bfr[4];
#pragma unroll
        for (int i = 0; i < 4; ++i)
            af[i] = *(const bf16x8*)&lA[(wr * 64 + i * 16 + lm) * 32 + q * 8];
#pragma unroll
        for (int j = 0; j < 4; ++j)
            bfr[j] = *(const bf16x8*)&lB[(wc * 64 + j * 16 + lm) * 32 + q * 8];
#pragma unroll
        for (int i = 0; i < 4; ++i)
#pragma unroll
            for (int j = 0; j < 4; ++j)
                acc[i][j] = __builtin_amdgcn_mfma_f32_16x16x32_bf16(
                    af[i], bfr[j], acc[i][j], 0, 0, 0);
        __syncthreads();
    }

    // epilogue: C/D layout col=lane&15, row=(lane>>4)*4+reg
#pragma unroll
    for (int j = 0; j < 4; ++j) {
        const int col = n0 + wc * 64 + j * 16 + lm;
        const float bv = bias[col];
#pragma unroll
        for (int i = 0; i < 4; ++i) {
            const int row = m0 + wr * 64 + i * 16 + q * 4;
#pragma unroll
            for (int r = 0; r < 4; ++r)
                C[(size_t)(row + r) * N_DIM + col] = acc[i][j][r] + bv;
        }
    }
}

// ---------------- Fallback: fused gather GEMM, zero workspace ----------------
__global__ __launch_bounds__(256) void gemm_fused(const float* __restrict__ X,
                                                  const float* __restrict__ table,
                                                  const void* __restrict__ rn_raw,
                                                  const float* __restrict__ bias,
                                                  float* __restrict__ C) {
    RN rn = decode_rn(rn_raw);
    const unsigned int stepu = (unsigned int)(rn.r3 % P_CONST);
    const unsigned int step32 =
        (unsigned int)(((unsigned long long)stepu * 32ull) % P_CONST);

    __shared__ __align__(16) unsigned short lA[128 * 32];
    __shared__ __align__(16) unsigned short lB[128 * 32];
    const int t = threadIdx.x;
    const int m0 = blockIdx.y * 128;
    const int n0 = blockIdx.x * 128;
    const int lane = t & 63;
    const int w = t >> 6;
    const int wr = w >> 1, wc = w & 1;
    const int lm = lane & 15, q = lane >> 4;

    unsigned int curB[2];
    int rowB[2], colB[2];
#pragma unroll
    for (int e = 0; e < 2; ++e) {
        const int c = t + e * 256;
        rowB[e] = c >> 2;
        colB[e] = (c & 3) * 8;
        const unsigned long long base =
            ((unsigned long long)(n0 + rowB[e]) * rn.r2 + rn.r1) % P_CONST;
        curB[e] =
            (unsigned int)((base + (unsigned long long)colB[e] * stepu) % P_CONST);
    }

    f32x4 acc[4][4] = {};

    for (int k0 = 0; k0 < K_DIM; k0 += 32) {
#pragma unroll
        for (int c = t; c < 1024; c += 256) {
            const int row = c >> 3, col = (c & 7) * 4;
            const float4 v =
                *(const float4*)(X + (size_t)(m0 + row) * K_DIM + k0 + col);
            ushort4 o;
            o.x = f2bf(v.x); o.y = f2bf(v.y); o.z = f2bf(v.z); o.w = f2bf(v.w);
            *(ushort4*)&lA[row * 32 + col] = o;
        }
#pragma unroll
        for (int e = 0; e < 2; ++e) {
            unsigned int cur = curB[e];
            union { unsigned short s[8]; uint4 v; } o;
#pragma unroll
            for (int i = 0; i < 8; ++i) {
                o.s[i] = f2bf(table[cur & HASH_MASK]);
                cur += stepu;
                if (cur >= P_CONST) cur -= P_CONST;
            }
            curB[e] += step32;
            if (curB[e] >= P_CONST) curB[e] -= P_CONST;
            *(uint4*)&lB[rowB[e] * 32 + colB[e]] = o.v;
        }
        __syncthreads();

        bf16x8 af[4], bfr[4];
#pragma unroll
        for (int i = 0; i < 4; ++i)
            af[i] = *(const bf16x8*)&lA[(wr * 64 + i * 16 + lm) * 32 + q * 8];
#pragma unroll
        for (int j = 0; j < 4; ++j)
            bfr[j] = *(const bf16x8*)&lB[(wc * 64 + j * 16 + lm) * 32 + q * 8];
#pragma unroll
        for (int i = 0; i < 4; ++i)
#pragma unroll
            for (int j = 0; j < 4; ++j)
                acc[i][j] = __builtin_amdgcn_mfma_f32_16x16x32_bf16(
                    af[i], bfr[j], acc[i][j], 0, 0, 0);
        __syncthreads();
    }

#pragma unroll
    for (int j = 0; j < 4; ++j) {
        const int col = n0 + wc * 64 + j * 16 + lm;
        const float bv = bias[col];
#pragma unroll
        for (int i = 0; i < 4; ++i) {
            const int row = m0 + wr * 64 + i * 16 + q * 4;
#pragma unroll
            for (int r = 0; r < 4; ++r)
                C[(size_t)(row + r) * N_DIM + col] = acc[i][j][r] + bv;
        }
    }
}

extern "C" void kernel_launch(void* const* d_in, const int* in_sizes, int n_in,
                              void* d_out, int out_size, void* d_ws, size_t ws_size,
                              hipStream_t stream) {
    const float* x = (const float*)d_in[0];
    const float* hw = (const float*)d_in[1];
    const void* rn = d_in[2];
    const float* bias = (const float*)d_in[3];
    float* out = (float*)d_out;

    const size_t wt_bytes = (size_t)N_DIM * K_DIM * 2;  // 32 MB
    const size_t xb_bytes = (size_t)M_DIM * K_DIM * 2;  // 64 MB

    if (ws_size >= wt_bytes + xb_bytes) {
        unsigned short* Wt = (unsigned short*)d_ws;
        unsigned short* Xb = (unsigned short*)((char*)d_ws + wt_bytes);
        // 4096 Wt-row blocks + 16384 cvt blocks, interleaved 1:4
        prep<<<20480, 256, 0, stream>>>(x, hw, rn, Wt, Xb);
        gemm_bt<<<dim3(N_DIM / 128, M_DIM / 128), 256, 0, stream>>>(Xb, Wt, bias, out);
    } else {
        gemm_fused<<<dim3(N_DIM / 128, M_DIM / 128), 256, 0, stream>>>(x, hw, rn, bias, out);
    }
}

// Round 4
// 598.927 us; speedup vs baseline: 1.0406x; 1.0406x over previous
//
#include <hip/hip_runtime.h>
#include <stdint.h>

// RzLinear: out[M,N] = x[M,K] @ W[K,N] + bias, W[k,n] = table[((k*r3+n*r2+r1)%P)%H]
// R4 = R3 with compile fix: __builtin_nontemporal_* requires clang ext_vector_type,
// not HIP_vector_type (float4/uint4 are classes). Theory unchanged:
// gathers were L2-thrash-bound (4MB fp32 table == per-XCD L2; streams evicted it).
// Fix: bf16 table (2MB, L2-resident) + nt-flagged streaming loads/stores in prep.
// GEMM (m97 structure, ~800 TF at this shape) unchanged.

#define P_CONST 56598313u
#define HASH_MASK 0xFFFFFu
#define M_DIM 8192
#define N_DIM 4096
#define K_DIM 4096

typedef __attribute__((ext_vector_type(8))) short bf16x8;
typedef __attribute__((ext_vector_type(4))) float f32x4;
typedef __attribute__((ext_vector_type(4))) float fvec4;       // for nt load
typedef __attribute__((ext_vector_type(4))) unsigned int uvec4; // for nt store

__device__ __forceinline__ unsigned short f2bf(float f) {
    unsigned int u = __float_as_uint(f);
    return (unsigned short)((u + 0x7FFFu + ((u >> 16) & 1u)) >> 16);  // RNE
}

struct RN { unsigned long long r1, r2, r3; };

__device__ __forceinline__ RN decode_rn(const void* rn_raw) {
    RN o;
    const long long* rn64 = (const long long*)rn_raw;
    if (rn64[0] == 56598313LL) {
        o.r1 = (unsigned long long)rn64[1];
        o.r2 = (unsigned long long)rn64[2];
        o.r3 = (unsigned long long)rn64[3];
    } else {
        const int* rn32 = (const int*)rn_raw;
        o.r1 = (unsigned long long)(unsigned int)rn32[1];
        o.r2 = (unsigned long long)(unsigned int)rn32[2];
        o.r3 = (unsigned long long)(unsigned int)rn32[3];
    }
    return o;
}

__device__ __forceinline__ void load16(const void* g, void* l) {
    __builtin_amdgcn_global_load_lds(
        (const __attribute__((address_space(1))) void*)g,
        (__attribute__((address_space(3))) void*)l,
        16, 0, 0);
}

// -------- Phase 0: tableB = bf16(table), 4MB -> 2MB (keeps L2-resident later)
__global__ __launch_bounds__(256) void cvt_table(const float* __restrict__ table,
                                                 unsigned short* __restrict__ tableB) {
    const size_t i8 = ((size_t)blockIdx.x * 256 + threadIdx.x) * 8;
    const fvec4 a = __builtin_nontemporal_load((const fvec4*)(table + i8));
    const fvec4 b = __builtin_nontemporal_load((const fvec4*)(table + i8 + 4));
    union { unsigned short s[8]; uvec4 v; } o;
    o.s[0] = f2bf(a.x); o.s[1] = f2bf(a.y); o.s[2] = f2bf(a.z); o.s[3] = f2bf(a.w);
    o.s[4] = f2bf(b.x); o.s[5] = f2bf(b.y); o.s[6] = f2bf(b.z); o.s[7] = f2bf(b.w);
    *(uvec4*)(tableB + i8) = o.v;  // normal store: want tableB cached
}

// -------- Phase 1 (mixed grid): Wt[n][k] = tableB[hash(k,n)]  and  Xb = bf16(x)
// b%5==0 -> gather one Wt row (4096 rows); else stream-convert an x chunk.
// All streaming traffic is nt-flagged so the 2MB tableB stays L2-resident.
__global__ __launch_bounds__(256) void prep(const float* __restrict__ x,
                                            const unsigned short* __restrict__ tableB,
                                            const void* __restrict__ rn_raw,
                                            unsigned short* __restrict__ Wt,
                                            unsigned short* __restrict__ Xb) {
    const int b = blockIdx.x;
    const int t = threadIdx.x;
    if (b % 5 == 0) {
        RN rn = decode_rn(rn_raw);
        const unsigned int stepu = (unsigned int)(rn.r3 % P_CONST);
        const unsigned int n = (unsigned int)(b / 5);
        const unsigned long long base =
            ((unsigned long long)n * rn.r2 + rn.r1) % P_CONST;
#pragma unroll
        for (int e = 0; e < 2; ++e) {
            const int k0 = (t + e * 256) * 8;
            unsigned int cur =
                (unsigned int)((base + (unsigned long long)k0 * stepu) % P_CONST);
            union { unsigned short s[8]; uvec4 v; } o;
#pragma unroll
            for (int i = 0; i < 8; ++i) {
                o.s[i] = tableB[cur & HASH_MASK];  // L2-hit gather (2B)
                cur += stepu;
                if (cur >= P_CONST) cur -= P_CONST;
            }
            __builtin_nontemporal_store(o.v, (uvec4*)(Wt + (size_t)n * K_DIM + k0));
        }
    } else {
        const int cb = b - (b / 5) - 1;  // 0..16383
        const size_t i8 = ((size_t)cb * 256 + t) * 8;
        const fvec4 a = __builtin_nontemporal_load((const fvec4*)(x + i8));
        const fvec4 bb = __builtin_nontemporal_load((const fvec4*)(x + i8 + 4));
        union { unsigned short s[8]; uvec4 v; } o;
        o.s[0] = f2bf(a.x);  o.s[1] = f2bf(a.y);
        o.s[2] = f2bf(a.z);  o.s[3] = f2bf(a.w);
        o.s[4] = f2bf(bb.x); o.s[5] = f2bf(bb.y);
        o.s[6] = f2bf(bb.z); o.s[7] = f2bf(bb.w);
        __builtin_nontemporal_store(o.v, (uvec4*)(Xb + i8));
    }
}

// ---------------- Phase 2: C = A @ Bt^T + bias (m97 structure) ----------------
__global__ __launch_bounds__(256) void gemm_bt(const unsigned short* __restrict__ A,
                                               const unsigned short* __restrict__ Bt,
                                               const float* __restrict__ bias,
                                               float* __restrict__ C) {
    __shared__ __align__(16) unsigned short lA[128 * 32];
    __shared__ __align__(16) unsigned short lB[128 * 32];
    const int t = threadIdx.x;
    const int m0 = blockIdx.y * 128;
    const int n0 = blockIdx.x * 128;
    const int lane = t & 63;
    const int w = t >> 6;
    const int wr = w >> 1, wc = w & 1;
    const int lm = lane & 15, q = lane >> 4;

    f32x4 acc[4][4] = {};

    for (int k0 = 0; k0 < K_DIM; k0 += 32) {
#pragma unroll
        for (int c = t; c < 512; c += 256) {
            const unsigned short* gp =
                A + (size_t)(m0 + (c >> 2)) * K_DIM + k0 + (c & 3) * 8;
            load16(gp, (char*)lA + (size_t)c * 16);
        }
#pragma unroll
        for (int c = t; c < 512; c += 256) {
            const unsigned short* gp =
                Bt + (size_t)(n0 + (c >> 2)) * K_DIM + k0 + (c & 3) * 8;
            load16(gp, (char*)lB + (size_t)c * 16);
        }
        __syncthreads();

        bf16x8 af[4], bfr[4];
#pragma unroll
        for (int i = 0; i < 4; ++i)
            af[i] = *(const bf16x8*)&lA[(wr * 64 + i * 16 + lm) * 32 + q * 8];
#pragma unroll
        for (int j = 0; j < 4; ++j)
            bfr[j] = *(const bf16x8*)&lB[(wc * 64 + j * 16 + lm) * 32 + q * 8];
#pragma unroll
        for (int i = 0; i < 4; ++i)
#pragma unroll
            for (int j = 0; j < 4; ++j)
                acc[i][j] = __builtin_amdgcn_mfma_f32_16x16x32_bf16(
                    af[i], bfr[j], acc[i][j], 0, 0, 0);
        __syncthreads();
    }

    // epilogue: C/D layout col=lane&15, row=(lane>>4)*4+reg
#pragma unroll
    for (int j = 0; j < 4; ++j) {
        const int col = n0 + wc * 64 + j * 16 + lm;
        const float bv = bias[col];
#pragma unroll
        for (int i = 0; i < 4; ++i) {
            const int row = m0 + wr * 64 + i * 16 + q * 4;
#pragma unroll
            for (int r = 0; r < 4; ++r)
                C[(size_t)(row + r) * N_DIM + col] = acc[i][j][r] + bv;
        }
    }
}

// ---------------- Fallback: fused gather GEMM, zero workspace ----------------
__global__ __launch_bounds__(256) void gemm_fused(const float* __restrict__ X,
                                                  const float* __restrict__ table,
                                                  const void* __restrict__ rn_raw,
                                                  const float* __restrict__ bias,
                                                  float* __restrict__ C) {
    RN rn = decode_rn(rn_raw);
    const unsigned int stepu = (unsigned int)(rn.r3 % P_CONST);
    const unsigned int step32 =
        (unsigned int)(((unsigned long long)stepu * 32ull) % P_CONST);

    __shared__ __align__(16) unsigned short lA[128 * 32];
    __shared__ __align__(16) unsigned short lB[128 * 32];
    const int t = threadIdx.x;
    const int m0 = blockIdx.y * 128;
    const int n0 = blockIdx.x * 128;
    const int lane = t & 63;
    const int w = t >> 6;
    const int wr = w >> 1, wc = w & 1;
    const int lm = lane & 15, q = lane >> 4;

    unsigned int curB[2];
    int rowB[2], colB[2];
#pragma unroll
    for (int e = 0; e < 2; ++e) {
        const int c = t + e * 256;
        rowB[e] = c >> 2;
        colB[e] = (c & 3) * 8;
        const unsigned long long base =
            ((unsigned long long)(n0 + rowB[e]) * rn.r2 + rn.r1) % P_CONST;
        curB[e] =
            (unsigned int)((base + (unsigned long long)colB[e] * stepu) % P_CONST);
    }

    f32x4 acc[4][4] = {};

    for (int k0 = 0; k0 < K_DIM; k0 += 32) {
#pragma unroll
        for (int c = t; c < 1024; c += 256) {
            const int row = c >> 3, col = (c & 7) * 4;
            const float4 v =
                *(const float4*)(X + (size_t)(m0 + row) * K_DIM + k0 + col);
            ushort4 o;
            o.x = f2bf(v.x); o.y = f2bf(v.y); o.z = f2bf(v.z); o.w = f2bf(v.w);
            *(ushort4*)&lA[row * 32 + col] = o;
        }
#pragma unroll
        for (int e = 0; e < 2; ++e) {
            unsigned int cur = curB[e];
            union { unsigned short s[8]; uint4 v; } o;
#pragma unroll
            for (int i = 0; i < 8; ++i) {
                o.s[i] = f2bf(table[cur & HASH_MASK]);
                cur += stepu;
                if (cur >= P_CONST) cur -= P_CONST;
            }
            curB[e] += step32;
            if (curB[e] >= P_CONST) curB[e] -= P_CONST;
            *(uint4*)&lB[rowB[e] * 32 + colB[e]] = o.v;
        }
        __syncthreads();

        bf16x8 af[4], bfr[4];
#pragma unroll
        for (int i = 0; i < 4; ++i)
            af[i] = *(const bf16x8*)&lA[(wr * 64 + i * 16 + lm) * 32 + q * 8];
#pragma unroll
        for (int j = 0; j < 4; ++j)
            bfr[j] = *(const bf16x8*)&lB[(wc * 64 + j * 16 + lm) * 32 + q * 8];
#pragma unroll
        for (int i = 0; i < 4; ++i)
#pragma unroll
            for (int j = 0; j < 4; ++j)
                acc[i][j] = __builtin_amdgcn_mfma_f32_16x16x32_bf16(
                    af[i], bfr[j], acc[i][j], 0, 0, 0);
        __syncthreads();
    }

#pragma unroll
    for (int j = 0; j < 4; ++j) {
        const int col = n0 + wc * 64 + j * 16 + lm;
        const float bv = bias[col];
#pragma unroll
        for (int i = 0; i < 4; ++i) {
            const int row = m0 + wr * 64 + i * 16 + q * 4;
#pragma unroll
            for (int r = 0; r < 4; ++r)
                C[(size_t)(row + r) * N_DIM + col] = acc[i][j][r] + bv;
        }
    }
}

extern "C" void kernel_launch(void* const* d_in, const int* in_sizes, int n_in,
                              void* d_out, int out_size, void* d_ws, size_t ws_size,
                              hipStream_t stream) {
    const float* x = (const float*)d_in[0];
    const float* hw = (const float*)d_in[1];
    const void* rn = d_in[2];
    const float* bias = (const float*)d_in[3];
    float* out = (float*)d_out;

    const size_t wt_bytes = (size_t)N_DIM * K_DIM * 2;        // 32 MB
    const size_t xb_bytes = (size_t)M_DIM * K_DIM * 2;        // 64 MB
    const size_t tb_bytes = (size_t)(HASH_MASK + 1) * 2;      // 2 MB

    if (ws_size >= wt_bytes + xb_bytes + tb_bytes) {
        unsigned short* Wt = (unsigned short*)d_ws;
        unsigned short* Xb = (unsigned short*)((char*)d_ws + wt_bytes);
        unsigned short* Tb = (unsigned short*)((char*)d_ws + wt_bytes + xb_bytes);
        cvt_table<<<(HASH_MASK + 1) / (8 * 256), 256, 0, stream>>>(hw, Tb);
        prep<<<20480, 256, 0, stream>>>(x, Tb, rn, Wt, Xb);
        gemm_bt<<<dim3(N_DIM / 128, M_DIM / 128), 256, 0, stream>>>(Xb, Wt, bias, out);
    } else {
        gemm_fused<<<dim3(N_DIM / 128, M_DIM / 128), 256, 0, stream>>>(x, hw, rn, bias, out);
    }
}